// Round 6
// baseline (147.220 us; speedup 1.0000x reference)
//
#include <hip/hip_runtime.h>

// AttentionConv on MI355X (gfx950) — fully fused.
// wprep: W[576][192] -> bf16 hi/lo, fragment-major (lane-coalesced) in d_ws.
// fused: per 64x64-px tile of one (b,c) plane:
//   1) stage 80x80 halo x-region (3 input ch) -> LDS bf16 hi/lo (10x10 patches)
//   2) M=128(pad 100 patches) x N=192(q,k,v x 64 dl) x K=192 bf16x3 MFMA GEMM
//   3) w=(k+bk)(v+bv), q -> LDS
//   4) separable 9-tap stencil: out = q * sum fr(di,pi)*fc(dj,pj)*w[neighbor]
// OOB halo patches: x=0 rows -> k,v = bias -> w = bk*bv automatically.

#define HW 512

typedef __attribute__((ext_vector_type(8))) short bf16x8;
typedef __attribute__((ext_vector_type(4))) float f32x4;

static __device__ __forceinline__ unsigned short bf16_rne(float f) {
    unsigned u = __builtin_bit_cast(unsigned, f);
    u += 0x7FFFu + ((u >> 16) & 1u);
    return (unsigned short)(u >> 16);
}
static __device__ __forceinline__ float bf16f(unsigned short h) {
    unsigned u = ((unsigned)h) << 16;
    return __builtin_bit_cast(float, u);
}

// ---------- prep: W -> fragment-major bf16 hi/lo ----------
// Ws[kt][half][kg 0..7][e 0..575][8 ushorts]; entry = W[e][kt*64 + kg*8 .. +7]
__global__ void __launch_bounds__(256) wprep_kernel(const float* __restrict__ W,
                                                    unsigned short* __restrict__ Ws)
{
    int gid = blockIdx.x * 256 + threadIdx.x;      // 13824 = 54*256 exact
    int e  = gid % 576;
    int t  = gid / 576;                            // 0..23
    int kg = t & 7;
    int kt = t >> 3;
    const float* src = W + (size_t)e*192 + kt*64 + kg*8;
    float4 a = ((const float4*)src)[0], b = ((const float4*)src)[1];
    float v[8] = {a.x, a.y, a.z, a.w, b.x, b.y, b.z, b.w};
    unsigned short h[8], lo[8];
    #pragma unroll
    for (int u = 0; u < 8; ++u) {
        h[u]  = bf16_rne(v[u]);
        lo[u] = bf16_rne(v[u] - bf16f(h[u]));
    }
    uint4 hp, lp;
    hp.x = (unsigned)h[0] | ((unsigned)h[1] << 16);
    hp.y = (unsigned)h[2] | ((unsigned)h[3] << 16);
    hp.z = (unsigned)h[4] | ((unsigned)h[5] << 16);
    hp.w = (unsigned)h[6] | ((unsigned)h[7] << 16);
    lp.x = (unsigned)lo[0] | ((unsigned)lo[1] << 16);
    lp.y = (unsigned)lo[2] | ((unsigned)lo[3] << 16);
    lp.z = (unsigned)lo[4] | ((unsigned)lo[5] << 16);
    lp.w = (unsigned)lo[6] | ((unsigned)lo[7] << 16);
    size_t oh = ((((size_t)kt*2 + 0)*8 + kg)*576 + e) * 8;
    size_t ol = ((((size_t)kt*2 + 1)*8 + kg)*576 + e) * 8;
    *(uint4*)(Ws + oh) = hp;
    *(uint4*)(Ws + ol) = lp;
}

// ---------- fused kernel ----------
__global__ void __launch_bounds__(512) fused_kernel(
    const float* __restrict__ x,
    const unsigned short* __restrict__ Ws,
    const float* __restrict__ bqkv,
    float* __restrict__ out)
{
    __shared__ char smem[44608];
    unsigned short* Ah = (unsigned short*)smem;            // [128][64] bf16, swizzled
    unsigned short* Al = (unsigned short*)(smem + 16384);
    float* w_lds = (float*)smem;                           // [100][68] (post-barrier)
    float* q_lds = (float*)(smem + 27200);                 // [64][68]

    const int tid = threadIdx.x;
    int bid = blockIdx.x;
    const int c  = bid % 3;
    int t2 = bid / 3;
    const int tx = t2 & 7;
    const int ty = (t2 >> 3) & 7;
    const int b  = t2 >> 6;

    const int wv = tid >> 6;          // wave 0..7
    const int l  = tid & 63;
    const int lr = l & 15;
    const int lk = l >> 4;
    const int wm = wv >> 1;           // M-group: patch rows wm*32..+31
    const int wn = wv & 1;            // dl half: wn*32

    f32x4 acc[2][6];                  // [mf][q0,q1,k0,k1,v0,v1]
    #pragma unroll
    for (int mf = 0; mf < 2; ++mf)
        #pragma unroll
        for (int sp = 0; sp < 6; ++sp)
            #pragma unroll
            for (int r = 0; r < 4; ++r) acc[mf][sp][r] = 0.f;

    const int gy0 = ty*64 - 8, gx0 = tx*64 - 8;

    for (int kt = 0; kt < 3; ++kt) {
        // ---- stage 80x80 x-region -> Ah/Al (bf16 hi/lo, XOR-swizzled) ----
        const float* xp = x + (size_t)(b*3 + kt) * HW * HW;
        #pragma unroll
        for (int it = 0; it < 4; ++it) {
            int f = tid + it*512;
            if (f < 1600) {                        // 80 rows x 20 float4
                int r  = f / 20;
                int c4 = f - r*20;
                int gy = gy0 + r;
                int gx = gx0 + c4*4;
                float4 v = make_float4(0.f, 0.f, 0.f, 0.f);
                if ((unsigned)gy < 512u && (unsigned)gx < 512u)
                    v = *(const float4*)(xp + (size_t)gy*HW + gx);
                int p  = (r >> 3)*10 + (c4 >> 1);          // halo patch 0..99
                int kk = (r & 7)*8 + (c4 & 1)*4;           // pi*8 + pj0
                unsigned short h0 = bf16_rne(v.x), h1 = bf16_rne(v.y),
                               h2 = bf16_rne(v.z), h3 = bf16_rne(v.w);
                unsigned short q0 = bf16_rne(v.x - bf16f(h0)), q1 = bf16_rne(v.y - bf16f(h1)),
                               q2 = bf16_rne(v.z - bf16f(h2)), q3 = bf16_rne(v.w - bf16f(h3));
                int byte = (p*128 + kk*2) ^ ((p & 7) << 4);
                *(uint2*)((char*)Ah + byte) = make_uint2((unsigned)h0 | ((unsigned)h1 << 16),
                                                         (unsigned)h2 | ((unsigned)h3 << 16));
                *(uint2*)((char*)Al + byte) = make_uint2((unsigned)q0 | ((unsigned)q1 << 16),
                                                         (unsigned)q2 | ((unsigned)q3 << 16));
            }
        }
        __syncthreads();

        // ---- GEMM over this kt (K=64, two 32-steps) ----
        const unsigned short* Wk = Ws + (size_t)kt * 2 * 8 * 576 * 8;
        #pragma unroll
        for (int ks = 0; ks < 2; ++ks) {
            bf16x8 ah[2], al[2];
            #pragma unroll
            for (int mf = 0; mf < 2; ++mf) {
                int row = wm*32 + mf*16 + lr;
                int byte = (row*128 + ks*64 + lk*16) ^ ((row & 7) << 4);
                ah[mf] = *(const bf16x8*)((const char*)Ah + byte);
                al[mf] = *(const bf16x8*)((const char*)Al + byte);
            }
            int kg = ks*4 + lk;
            const unsigned short* Bh = Wk + (size_t)(0*8 + kg) * 576 * 8;
            const unsigned short* Bl = Wk + (size_t)(1*8 + kg) * 576 * 8;
            #pragma unroll
            for (int sp = 0; sp < 6; ++sp) {
                int slot = sp >> 1, nf2 = sp & 1;
                int e = slot*192 + c*64 + wn*32 + nf2*16 + lr;
                bf16x8 bh = *(const bf16x8*)(Bh + (size_t)e * 8);
                bf16x8 bl = *(const bf16x8*)(Bl + (size_t)e * 8);
                #pragma unroll
                for (int mf = 0; mf < 2; ++mf) {
                    acc[mf][sp] = __builtin_amdgcn_mfma_f32_16x16x32_bf16(al[mf], bh, acc[mf][sp], 0, 0, 0);
                    acc[mf][sp] = __builtin_amdgcn_mfma_f32_16x16x32_bf16(ah[mf], bl, acc[mf][sp], 0, 0, 0);
                    acc[mf][sp] = __builtin_amdgcn_mfma_f32_16x16x32_bf16(ah[mf], bh, acc[mf][sp], 0, 0, 0);
                }
            }
        }
        __syncthreads();
    }

    // ---- epilogue: w = (k+bk)(v+bv) and q -> LDS ----
    float bq[2], bk[2], bv[2];
    #pragma unroll
    for (int nf2 = 0; nf2 < 2; ++nf2) {
        int dl = wn*32 + nf2*16 + lr;
        bq[nf2] = bqkv[      c*64 + dl];
        bk[nf2] = bqkv[192 + c*64 + dl];
        bv[nf2] = bqkv[384 + c*64 + dl];
    }
    #pragma unroll
    for (int mf = 0; mf < 2; ++mf)
        #pragma unroll
        for (int ri = 0; ri < 4; ++ri) {
            int p = wm*32 + mf*16 + lk*4 + ri;     // D row = (l>>4)*4 + reg
            if (p < 100) {
                #pragma unroll
                for (int nf2 = 0; nf2 < 2; ++nf2) {
                    int dl = wn*32 + nf2*16 + lr;
                    float wval = (acc[mf][2 + nf2][ri] + bk[nf2]) * (acc[mf][4 + nf2][ri] + bv[nf2]);
                    w_lds[p*68 + dl] = wval;
                }
                int pr = p / 10, pc = p - (p/10)*10;
                if (pr >= 1 && pr <= 8 && pc >= 1 && pc <= 8) {
                    int qi = (pr - 1)*8 + (pc - 1);
                    #pragma unroll
                    for (int nf2 = 0; nf2 < 2; ++nf2) {
                        int dl = wn*32 + nf2*16 + lr;
                        q_lds[qi*68 + dl] = acc[mf][nf2][ri] + bq[nf2];
                    }
                }
            }
        }
    __syncthreads();

    // ---- stencil: out = q * sum fr*fc*w ----
    #pragma unroll
    for (int it = 0; it < 2; ++it) {
        int e4  = tid + it*512;            // 0..1023
        int qi  = e4 >> 4;                 // core patch 0..63
        int dlq = e4 & 15;
        int dl0 = dlq << 2;
        int pi  = dl0 >> 3;
        int pj0 = dl0 & 7;                 // 0 or 4
        int p   = (1 + (qi >> 3))*10 + 1 + (qi & 7);
        float fr0 = __expf((float)(pi - 7) * 0.25f);
        float fr2 = __expf((float)(-pi) * 0.25f);
        float fa[4], fb[4];
        #pragma unroll
        for (int u = 0; u < 4; ++u) {
            int pj = pj0 + u;
            fa[u] = __expf((float)(pj - 7) * 0.25f);
            fb[u] = __expf((float)(-pj) * 0.25f);
        }
        float sx = 0.f, sy = 0.f, sz = 0.f, sw = 0.f;
        #pragma unroll
        for (int di = 0; di < 3; ++di) {
            const float* rowp = w_lds + (p + (di - 1)*10)*68 + dl0;
            float4 wl = *(const float4*)(rowp - 68);
            float4 wc = *(const float4*)(rowp);
            float4 wr = *(const float4*)(rowp + 68);
            float fr = (di == 0) ? fr0 : (di == 1) ? 1.f : fr2;
            sx += fr * (fa[0]*wl.x + wc.x + fb[0]*wr.x);
            sy += fr * (fa[1]*wl.y + wc.y + fb[1]*wr.y);
            sz += fr * (fa[2]*wl.z + wc.z + fb[2]*wr.z);
            sw += fr * (fa[3]*wl.w + wc.w + fb[3]*wr.w);
        }
        float4 q4 = *(const float4*)(q_lds + qi*68 + dl0);
        int y = ty*64 + (qi >> 3)*8 + pi;
        int xg = tx*64 + (qi & 7)*8 + pj0;
        float4 o;
        o.x = q4.x*sx; o.y = q4.y*sy; o.z = q4.z*sz; o.w = q4.w*sw;
        *(float4*)(out + ((size_t)(b*3 + c)*HW + y)*HW + xg) = o;
    }
}

extern "C" void kernel_launch(void* const* d_in, const int* in_sizes, int n_in,
                              void* d_out, int out_size, void* d_ws, size_t ws_size,
                              hipStream_t stream)
{
    const float* x  = (const float*)d_in[0];   // [8][3][512][512]
    const float* W  = (const float*)d_in[1];   // [576][192]
    const float* bq = (const float*)d_in[2];   // [576]
    unsigned short* Ws = (unsigned short*)d_ws; // 442 KB W-split

    wprep_kernel<<<54, 256, 0, stream>>>(W, Ws);
    fused_kernel<<<1536, 512, 0, stream>>>(x, Ws, bq, (float*)d_out);
}